// Round 1
// baseline (285.640 us; speedup 1.0000x reference)
//
#include <hip/hip_runtime.h>

// GQA forward, MI355X. Pipeline: cast/transpose -> Q & KV projection GEMMs
// (bf16 MFMA 16x16x32) -> flash attention (online softmax) -> out GEMM + bias.

typedef __attribute__((ext_vector_type(8))) short          bf16x8;
typedef __attribute__((ext_vector_type(4))) float          f32x4;
typedef __attribute__((ext_vector_type(4))) unsigned short u16x4;

#define DEV __device__ __forceinline__

static constexpr int BB  = 2;
static constexpr int SS  = 2048;
static constexpr int EMB = 1024;
static constexpr int NH  = 16;
static constexpr int HD  = 64;
static constexpr int KVD = 512;   // K cols (256) + V cols (256) fused

DEV unsigned short f2b(float f) {
  union { float f; unsigned u; } v; v.f = f;
  unsigned r = (v.u + 0x7FFFu + ((v.u >> 16) & 1u)) >> 16;  // RNE
  return (unsigned short)r;
}

DEV void gl_lds16(const void* g, void* l) {
  // async global->LDS, 16B/lane; LDS dest = wave-uniform base + lane*16
  __builtin_amdgcn_global_load_lds((__attribute__((address_space(1))) void*)g,
                                   (__attribute__((address_space(3))) void*)l,
                                   16, 0, 0);
}

// ---------------- elementwise cast: fp32 -> bf16, 4 elems/thread ----------
__global__ __launch_bounds__(256) void cast_x_kernel(const float* __restrict__ x,
                                                     unsigned short* __restrict__ xb) {
  size_t i = ((size_t)blockIdx.x * 256 + threadIdx.x) * 4;
  f32x4 f = *(const f32x4*)(x + i);
  u16x4 o;
  o[0] = f2b(f[0]); o[1] = f2b(f[1]); o[2] = f2b(f[2]); o[3] = f2b(f[3]);
  *(u16x4*)(xb + i) = o;
}

// ---------------- transpose + cast: W[K=1024][N] fp32 -> Wt[N][1024] bf16 --
__global__ __launch_bounds__(256) void transpose_cast_kernel(const float* __restrict__ W,
                                                             unsigned short* __restrict__ Wt,
                                                             int N) {
  __shared__ unsigned short tile[64][72];  // +8 pad breaks bank conflicts
  const int kb = blockIdx.x * 64, nb = blockIdx.y * 64;
  const int tid = threadIdx.x;
#pragma unroll
  for (int p = 0; p < 16; ++p) {
    int i = tid + 256 * p;              // 0..4095
    int k = i >> 6, n = i & 63;
    tile[k][n] = f2b(W[(size_t)(kb + k) * N + nb + n]);
  }
  __syncthreads();
#pragma unroll
  for (int p = 0; p < 16; ++p) {
    int i = tid + 256 * p;
    int n = i >> 6, k = i & 63;
    Wt[(size_t)(nb + n) * 1024 + kb + k] = tile[k][n];
  }
}

// ---------------- GEMM: C[M,N] = A[M,K] * Bt[N,K]^T  (all bf16 in) --------
// 64x128 tile, BK=32, 256 threads (4 waves, each 32x64 = 2x4 16x16 frags)
template <bool BF16_OUT, bool BIAS>
__global__ __launch_bounds__(256) void gemm_bt(const unsigned short* __restrict__ A,
                                               const unsigned short* __restrict__ Bt,
                                               void* __restrict__ Cv,
                                               const float* __restrict__ bias,
                                               int M, int N, int Kd) {
  const int tid = threadIdx.x;
  const int w = tid >> 6, lane = tid & 63;
  const int l15 = lane & 15, l4 = lane >> 4;
  const int wr = w >> 1, wc = w & 1;
  const size_t rb = (size_t)blockIdx.x * 64;
  const size_t cb = (size_t)blockIdx.y * 128;

  __shared__ alignas(16) unsigned short sA[64 * 32];
  __shared__ alignas(16) unsigned short sB[128 * 32];

  f32x4 acc[2][4] = {};

  const int srow = tid >> 2;            // 0..63
  const int scol = (tid & 3) * 8;       // 0,8,16,24
  const unsigned short* Ap = A + (rb + srow) * (size_t)Kd + scol;
  const unsigned short* Bp = Bt + (cb + srow) * (size_t)Kd + scol;

  for (int k0 = 0; k0 < Kd; k0 += 32) {
    __syncthreads();
    gl_lds16(Ap + k0, &sA[(16 * w) * 32]);
    gl_lds16(Bp + k0, &sB[(16 * w) * 32]);
    gl_lds16(Bp + 64 * (size_t)Kd + k0, &sB[(64 + 16 * w) * 32]);
    asm volatile("s_waitcnt vmcnt(0)" ::: "memory");
    __syncthreads();

    bf16x8 af[2], bf[4];
#pragma unroll
    for (int m = 0; m < 2; ++m)
      af[m] = *(const bf16x8*)&sA[(wr * 32 + m * 16 + l15) * 32 + 8 * l4];
#pragma unroll
    for (int n = 0; n < 4; ++n)
      bf[n] = *(const bf16x8*)&sB[(wc * 64 + n * 16 + l15) * 32 + 8 * l4];
#pragma unroll
    for (int m = 0; m < 2; ++m)
#pragma unroll
      for (int n = 0; n < 4; ++n)
        acc[m][n] = __builtin_amdgcn_mfma_f32_16x16x32_bf16(af[m], bf[n], acc[m][n], 0, 0, 0);
  }

  if constexpr (BF16_OUT) {
    unsigned short* C = (unsigned short*)Cv;
#pragma unroll
    for (int m = 0; m < 2; ++m)
#pragma unroll
      for (int n = 0; n < 4; ++n)
#pragma unroll
        for (int r = 0; r < 4; ++r) {
          size_t row = rb + wr * 32 + m * 16 + 4 * l4 + r;
          size_t col = cb + wc * 64 + n * 16 + l15;
          C[row * N + col] = f2b(acc[m][n][r]);
        }
  } else {
    float* C = (float*)Cv;
    float bv[4] = {0.f, 0.f, 0.f, 0.f};
    if constexpr (BIAS) {
#pragma unroll
      for (int n = 0; n < 4; ++n) bv[n] = bias[cb + wc * 64 + n * 16 + l15];
    }
#pragma unroll
    for (int m = 0; m < 2; ++m)
#pragma unroll
      for (int n = 0; n < 4; ++n)
#pragma unroll
        for (int r = 0; r < 4; ++r) {
          size_t row = rb + wr * 32 + m * 16 + 4 * l4 + r;
          size_t col = cb + wc * 64 + n * 16 + l15;
          C[row * N + col] = acc[m][n][r] + bv[n];
        }
  }
}

// ---------------- flash attention -----------------------------------------
// grid (S/64, B*H), 256 threads; wave w owns 16 q-rows. KV tile = 64.
// Q [4096][1024] bf16 (col h*64+d); KV [4096][512] bf16 (K at g*64+d, V at 256+g*64+d)
__global__ __launch_bounds__(256) void attn_kernel(const unsigned short* __restrict__ Qb,
                                                   const unsigned short* __restrict__ KVb,
                                                   unsigned short* __restrict__ Ctx) {
  const int qi = blockIdx.x;
  const int bh = blockIdx.y;
  const int b = bh >> 4, h = bh & 15, g = h >> 2;
  const int tid = threadIdx.x;
  const int w = tid >> 6, lane = tid & 63;
  const int l15 = lane & 15, l4 = lane >> 4;

  __shared__ alignas(16) unsigned short Vt[64][64];      // V^T, XOR-swizzled 16B blocks
  __shared__ alignas(16) unsigned short Pl[4][16][64];   // per-wave P, swizzled

  const int qrow = qi * 64 + w * 16;
  const unsigned short* qp = Qb + ((size_t)(b * SS + qrow + l15)) * 1024 + h * 64 + 8 * l4;
  bf16x8 qf0 = *(const bf16x8*)(qp);
  bf16x8 qf1 = *(const bf16x8*)(qp + 32);

  f32x4 o[4] = {};
  float m_r[4], l_r[4];
#pragma unroll
  for (int r = 0; r < 4; ++r) { m_r[r] = -1e30f; l_r[r] = 0.f; }

  for (int kt = 0; kt <= qi; ++kt) {
    const int kv0 = kt * 64;
    __syncthreads();  // protect Vt from previous iteration's readers
    // stage V^T into LDS (row d, col kv), 16B-block XOR swizzle
#pragma unroll
    for (int p = 0; p < 2; ++p) {
      int c = tid + 256 * p;        // 0..511
      int kv = c >> 3, d0 = (c & 7) * 8;
      const unsigned short* vp =
          KVb + ((size_t)(b * SS + kv0 + kv)) * KVD + 256 + g * 64 + d0;
      bf16x8 vv = *(const bf16x8*)vp;
#pragma unroll
      for (int j = 0; j < 8; ++j) {
        int d = d0 + j;
        int blk = ((kv >> 3) ^ (d & 7) ^ (d >> 3)) & 7;
        Vt[d][blk * 8 + (kv & 7)] = (unsigned short)vv[j];
      }
    }
    __syncthreads();

    // S = (Q K^T) * 0.125, K fragments straight from global (L2-resident)
    f32x4 sa[4];
    const unsigned short* kp =
        KVb + ((size_t)(b * SS + kv0 + l15)) * KVD + g * 64 + 8 * l4;
#pragma unroll
    for (int c = 0; c < 4; ++c) {
      bf16x8 kf0 = *(const bf16x8*)(kp + (size_t)c * 16 * KVD);
      bf16x8 kf1 = *(const bf16x8*)(kp + (size_t)c * 16 * KVD + 32);
      f32x4 z = {0.f, 0.f, 0.f, 0.f};
      z = __builtin_amdgcn_mfma_f32_16x16x32_bf16(qf0, kf0, z, 0, 0, 0);
      z = __builtin_amdgcn_mfma_f32_16x16x32_bf16(qf1, kf1, z, 0, 0, 0);
      sa[c] = z;
    }

    float rmax[4] = {-1e30f, -1e30f, -1e30f, -1e30f};
#pragma unroll
    for (int c = 0; c < 4; ++c)
#pragma unroll
      for (int r = 0; r < 4; ++r) {
        float v = sa[c][r] * 0.125f;
        if (kt == qi && (c * 16 + l15) > (w * 16 + 4 * l4 + r)) v = -1e30f;  // causal
        sa[c][r] = v;
        rmax[r] = fmaxf(rmax[r], v);
      }
#pragma unroll
    for (int r = 0; r < 4; ++r) {
      float v = rmax[r];
      v = fmaxf(v, __shfl_xor(v, 1));
      v = fmaxf(v, __shfl_xor(v, 2));
      v = fmaxf(v, __shfl_xor(v, 4));
      v = fmaxf(v, __shfl_xor(v, 8));
      rmax[r] = v;
    }
    float corr[4], rsum[4];
#pragma unroll
    for (int r = 0; r < 4; ++r) {
      float mn = fmaxf(m_r[r], rmax[r]);
      corr[r] = __expf(m_r[r] - mn);
      m_r[r] = mn;
      rsum[r] = 0.f;
    }
    // P = exp(S - m), stash bf16 into per-wave LDS (re-layout for PV A-frag)
#pragma unroll
    for (int c = 0; c < 4; ++c)
#pragma unroll
      for (int r = 0; r < 4; ++r) {
        float p = __expf(sa[c][r] - m_r[r]);
        rsum[r] += p;
        int row = 4 * l4 + r, col = c * 16 + l15;
        Pl[w][row][(((col >> 3) ^ row) & 7) * 8 + (col & 7)] = f2b(p);
      }
#pragma unroll
    for (int r = 0; r < 4; ++r) {
      float v = rsum[r];
      v += __shfl_xor(v, 1); v += __shfl_xor(v, 2);
      v += __shfl_xor(v, 4); v += __shfl_xor(v, 8);
      l_r[r] = l_r[r] * corr[r] + v;
    }
#pragma unroll
    for (int t = 0; t < 4; ++t)
#pragma unroll
      for (int r = 0; r < 4; ++r) o[t][r] *= corr[r];

    // O += P V
#pragma unroll
    for (int ks = 0; ks < 2; ++ks) {
      bf16x8 pf = *(const bf16x8*)&Pl[w][l15][(((ks * 4 + l4) ^ (l15 & 7)) & 7) * 8];
#pragma unroll
      for (int t = 0; t < 4; ++t) {
        int d = t * 16 + l15;
        int blk = ((ks * 4 + l4) ^ (d & 7) ^ (d >> 3)) & 7;
        bf16x8 vf = *(const bf16x8*)&Vt[d][blk * 8];
        o[t] = __builtin_amdgcn_mfma_f32_16x16x32_bf16(pf, vf, o[t], 0, 0, 0);
      }
    }
  }

#pragma unroll
  for (int t = 0; t < 4; ++t)
#pragma unroll
    for (int r = 0; r < 4; ++r) {
      float v = o[t][r] / l_r[r];
      Ctx[((size_t)(b * SS + qrow + 4 * l4 + r)) * 1024 + h * 64 + t * 16 + l15] = f2b(v);
    }
}

// ---------------------------------------------------------------------------
extern "C" void kernel_launch(void* const* d_in, const int* in_sizes, int n_in,
                              void* d_out, int out_size, void* d_ws, size_t ws_size,
                              hipStream_t stream) {
  (void)in_sizes; (void)n_in; (void)out_size; (void)ws_size;
  const float* x  = (const float*)d_in[0];
  const float* Wq = (const float*)d_in[1];
  const float* Wk = (const float*)d_in[2];
  const float* Wv = (const float*)d_in[3];
  const float* Wo = (const float*)d_in[4];
  const float* bo = (const float*)d_in[5];
  float* out = (float*)d_out;

  char* ws = (char*)d_ws;
  unsigned short* x_bf  = (unsigned short*)(ws);                       // 8 MiB
  unsigned short* Qb    = (unsigned short*)(ws + (size_t)( 8u << 20)); // 8 MiB
  unsigned short* KVb   = (unsigned short*)(ws + (size_t)(16u << 20)); // 4 MiB
  unsigned short* Ctx   = (unsigned short*)(ws + (size_t)(20u << 20)); // 8 MiB
  unsigned short* Wq_t  = (unsigned short*)(ws + (size_t)(28u << 20)); // 2 MiB
  unsigned short* Wkv_t = (unsigned short*)(ws + (size_t)(30u << 20)); // 1 MiB
  unsigned short* Wo_t  = (unsigned short*)(ws + (size_t)(31u << 20)); // 2 MiB

  const int M = BB * SS;  // 4096

  cast_x_kernel<<<dim3((M * EMB) / (256 * 4)), 256, 0, stream>>>(x, x_bf);
  transpose_cast_kernel<<<dim3(16, 16), 256, 0, stream>>>(Wq, Wq_t, 1024);
  transpose_cast_kernel<<<dim3(16, 4),  256, 0, stream>>>(Wk, Wkv_t, 256);
  transpose_cast_kernel<<<dim3(16, 4),  256, 0, stream>>>(Wv, Wkv_t + (size_t)256 * 1024, 256);
  transpose_cast_kernel<<<dim3(16, 16), 256, 0, stream>>>(Wo, Wo_t, 1024);

  gemm_bt<true, false><<<dim3(M / 64, EMB / 128), 256, 0, stream>>>(
      x_bf, Wq_t, Qb, nullptr, M, EMB, EMB);
  gemm_bt<true, false><<<dim3(M / 64, KVD / 128), 256, 0, stream>>>(
      x_bf, Wkv_t, KVb, nullptr, M, KVD, EMB);

  attn_kernel<<<dim3(SS / 64, BB * NH), 256, 0, stream>>>(Qb, KVb, Ctx);

  gemm_bt<false, true><<<dim3(M / 64, EMB / 128), 256, 0, stream>>>(
      Ctx, Wo_t, out, bo, M, EMB, EMB);
}